// Round 1
// baseline (1570.897 us; speedup 1.0000x reference)
//
#include <hip/hip_runtime.h>
#include <stdint.h>

typedef __bf16 bf16_t;
typedef __bf16 bf16x8 __attribute__((ext_vector_type(8)));
typedef float f32x4 __attribute__((ext_vector_type(4)));

#define DEV_INLINE __device__ __forceinline__

// ---- async global->LDS (16B per lane), CK-style addrspace casts ----
DEV_INLINE void async_ld16(const void* g, void* l) {
  __builtin_amdgcn_global_load_lds(
      (const __attribute__((address_space(1))) void*)(uintptr_t)g,
      (__attribute__((address_space(3))) void*)(unsigned)(uintptr_t)l,
      16, 0, 0);
}

// ---- wave (64-lane) reductions ----
DEV_INLINE float wred_sum(float v) {
#pragma unroll
  for (int o = 32; o; o >>= 1) v += __shfl_xor(v, o, 64);
  return v;
}
DEV_INLINE float wred_max(float v) {
#pragma unroll
  for (int o = 32; o; o >>= 1) v = fmaxf(v, __shfl_xor(v, o, 64));
  return v;
}

// =====================================================================
// Generic MFMA bf16 GEMM:  C[m,n] = sum_k A[m,k] * Bt[n,k]  (+bias/res/relu)
// Tile 128x128, BK=64, 256 threads (4 waves, each 64x64), 16x16x32 MFMA.
// LDS chunks XOR-swizzled (chunk^row&7) -> conflict-free ds_read_b128.
// FLAGS: 1=bias 2=relu 4=residual(f32) 8=out bf16 16=causal tile skip
//        32=causal K limit (K <= m0+128)
// =====================================================================
template <int FLAGS>
__global__ __launch_bounds__(256) void gemm_bt(
    const bf16_t* __restrict__ A, const bf16_t* __restrict__ Bt,
    void* __restrict__ Cv, const float* __restrict__ bias,
    const float* __restrict__ res, int K, int lda, int ldb, int ldc, int zdiv,
    long As_b, long As_h, long Bs_b, long Bs_h, long Cs_b, long Cs_h) {
  constexpr bool HAS_BIAS = (FLAGS & 1) != 0;
  constexpr bool RELU     = (FLAGS & 2) != 0;
  constexpr bool HAS_RES  = (FLAGS & 4) != 0;
  constexpr bool OUT_BF16 = (FLAGS & 8) != 0;
  constexpr bool CSKIP    = (FLAGS & 16) != 0;
  constexpr bool KLIM     = (FLAGS & 32) != 0;

  int bx = blockIdx.x, by = blockIdx.y, z = blockIdx.z;
  if constexpr (CSKIP) {
    if (bx > by) return;  // tile entirely above causal diagonal
  }
  int zb = z / zdiv, zh = z - zb * zdiv;
  const bf16_t* Ap = A + zb * As_b + zh * As_h;
  const bf16_t* Bp = Bt + zb * Bs_b + zh * Bs_h;
  long offC = zb * Cs_b + zh * Cs_h;

  int m0 = by * 128, n0 = bx * 128;
  int Keff = K;
  if constexpr (KLIM) Keff = (K < m0 + 128) ? K : (m0 + 128);

  __shared__ __align__(16) bf16_t As[128 * 64];
  __shared__ __align__(16) bf16_t Bs[128 * 64];

  int tid = threadIdx.x;
  int lane = tid & 63, wave = tid >> 6;
  int wm = (wave >> 1) * 64, wn = (wave & 1) * 64;
  int l16 = lane & 15, quad = lane >> 4;

  f32x4 acc[4][4] = {};

  for (int k0 = 0; k0 < Keff; k0 += 64) {
#pragma unroll
    for (int r = 0; r < 4; ++r) {
      int c = r * 256 + tid;
      int row = c >> 3, cc = c & 7;
      int sc = cc ^ (row & 7);  // global chunk fetched into LDS slot cc
      async_ld16(Ap + (long)(m0 + row) * lda + (k0 + sc * 8), As + c * 8);
      async_ld16(Bp + (long)(n0 + row) * ldb + (k0 + sc * 8), Bs + c * 8);
    }
    asm volatile("s_waitcnt vmcnt(0)" ::: "memory");
    __syncthreads();
#pragma unroll
    for (int s = 0; s < 2; ++s) {
      bf16x8 af[4], bfr[4];
#pragma unroll
      for (int mi = 0; mi < 4; ++mi) {
        int row = wm + mi * 16 + l16;
        int ch = (s * 4 + quad) ^ (row & 7);
        af[mi] = *(const bf16x8*)(As + row * 64 + ch * 8);
      }
#pragma unroll
      for (int ni = 0; ni < 4; ++ni) {
        int row = wn + ni * 16 + l16;
        int ch = (s * 4 + quad) ^ (row & 7);
        bfr[ni] = *(const bf16x8*)(Bs + row * 64 + ch * 8);
      }
#pragma unroll
      for (int mi = 0; mi < 4; ++mi)
#pragma unroll
        for (int ni = 0; ni < 4; ++ni)
          acc[mi][ni] = __builtin_amdgcn_mfma_f32_16x16x32_bf16(
              af[mi], bfr[ni], acc[mi][ni], 0, 0, 0);
    }
    __syncthreads();
  }

  // epilogue: C/D layout col=lane&15, row=quad*4+i (m89/m91 verified)
#pragma unroll
  for (int mi = 0; mi < 4; ++mi) {
#pragma unroll
    for (int ni = 0; ni < 4; ++ni) {
      int gr = m0 + wm + mi * 16 + quad * 4;
      int gc = n0 + wn + ni * 16 + l16;
      float bv = 0.f;
      if constexpr (HAS_BIAS) bv = bias[gc];
#pragma unroll
      for (int i = 0; i < 4; ++i) {
        long o = offC + (long)(gr + i) * ldc + gc;
        float v = acc[mi][ni][i];
        if constexpr (HAS_BIAS) v += bv;
        if constexpr (HAS_RES) v += res[o];
        if constexpr (RELU) v = fmaxf(v, 0.f);
        if constexpr (OUT_BF16)
          ((bf16_t*)Cv)[o] = (bf16_t)v;
        else
          ((float*)Cv)[o] = v;
      }
    }
  }
}

// ---- fp32 [R,C] -> bf16 [C,R] transpose (32x32 LDS tile) ----
__global__ __launch_bounds__(256) void transpose_cast(
    const float* __restrict__ in, bf16_t* __restrict__ out, int R, int Ccols,
    long in_z, long out_z) {
  __shared__ float tile[32][33];
  long zi = (long)blockIdx.z;
  const float* ip = in + zi * in_z;
  bf16_t* op = out + zi * out_z;
  int tx = threadIdx.x & 31, ty = threadIdx.x >> 5;
  int r0 = blockIdx.y * 32, c0 = blockIdx.x * 32;
#pragma unroll
  for (int j = 0; j < 4; ++j)
    tile[ty + j * 8][tx] = ip[(long)(r0 + ty + j * 8) * Ccols + c0 + tx];
  __syncthreads();
#pragma unroll
  for (int j = 0; j < 4; ++j)
    op[(long)(c0 + ty + j * 8) * R + r0 + tx] = (bf16_t)tile[tx][ty + j * 8];
}

// ---- embedding gather + LayerNorm1: x (f32), h = LN(x) (bf16) ----
__global__ __launch_bounds__(256) void embed_ln1(
    const int* __restrict__ idx, const float* __restrict__ tok,
    const float* __restrict__ pos, const float* __restrict__ g,
    const float* __restrict__ bb, float* __restrict__ x,
    bf16_t* __restrict__ h) {
  int row = blockIdx.x;       // b*T + t
  int t = row & 2047;
  int tid = threadIdx.x;
  int token = idx[row];
  float4 a = ((const float4*)(tok + (size_t)token * 1024))[tid];
  float4 p = ((const float4*)(pos + (size_t)t * 1024))[tid];
  float4 v = make_float4(a.x + p.x, a.y + p.y, a.z + p.z, a.w + p.w);
  ((float4*)(x + (size_t)row * 1024))[tid] = v;
  float s1 = v.x + v.y + v.z + v.w;
  float s2 = v.x * v.x + v.y * v.y + v.z * v.z + v.w * v.w;
  __shared__ float shA[4], shB[4];
  s1 = wred_sum(s1);
  s2 = wred_sum(s2);
  int lane = tid & 63, wv = tid >> 6;
  if (lane == 0) { shA[wv] = s1; shB[wv] = s2; }
  __syncthreads();
  float S1 = shA[0] + shA[1] + shA[2] + shA[3];
  float S2 = shB[0] + shB[1] + shB[2] + shB[3];
  float mu = S1 * (1.f / 1024.f);
  float var = S2 * (1.f / 1024.f) - mu * mu;
  float rstd = rsqrtf(var + 1e-5f);
  int c = tid * 4;
  float4 gv = ((const float4*)g)[tid];
  float4 bv = ((const float4*)bb)[tid];
  bf16_t* hp = h + (size_t)row * 1024 + c;
  hp[0] = (bf16_t)((v.x - mu) * rstd * gv.x + bv.x);
  hp[1] = (bf16_t)((v.y - mu) * rstd * gv.y + bv.y);
  hp[2] = (bf16_t)((v.z - mu) * rstd * gv.z + bv.z);
  hp[3] = (bf16_t)((v.w - mu) * rstd * gv.w + bv.w);
}

// ---- residual add (attn in [B,H,T,D]) + LayerNorm2 ----
__global__ __launch_bounds__(256) void ln2_res(
    const float* __restrict__ x, const float* __restrict__ attn,
    const float* __restrict__ g, const float* __restrict__ bb,
    float* __restrict__ x2, bf16_t* __restrict__ h2) {
  int row = blockIdx.x;
  int b = row >> 11, t = row & 2047;
  int tid = threadIdx.x;
  int c = tid * 4;
  int hh = c >> 8, d = c & 255;
  float4 xv = ((const float4*)(x + (size_t)row * 1024))[tid];
  float4 av = *(const float4*)(attn + ((size_t)(b * 4 + hh) * 2048 + t) * 256 + d);
  float4 v = make_float4(xv.x + av.x, xv.y + av.y, xv.z + av.z, xv.w + av.w);
  ((float4*)(x2 + (size_t)row * 1024))[tid] = v;
  float s1 = v.x + v.y + v.z + v.w;
  float s2 = v.x * v.x + v.y * v.y + v.z * v.z + v.w * v.w;
  __shared__ float shA[4], shB[4];
  s1 = wred_sum(s1);
  s2 = wred_sum(s2);
  int lane = tid & 63, wv = tid >> 6;
  if (lane == 0) { shA[wv] = s1; shB[wv] = s2; }
  __syncthreads();
  float S1 = shA[0] + shA[1] + shA[2] + shA[3];
  float S2 = shB[0] + shB[1] + shB[2] + shB[3];
  float mu = S1 * (1.f / 1024.f);
  float var = S2 * (1.f / 1024.f) - mu * mu;
  float rstd = rsqrtf(var + 1e-5f);
  float4 gv = ((const float4*)g)[tid];
  float4 bv = ((const float4*)bb)[tid];
  bf16_t* hp = h2 + (size_t)row * 1024 + c;
  hp[0] = (bf16_t)((v.x - mu) * rstd * gv.x + bv.x);
  hp[1] = (bf16_t)((v.y - mu) * rstd * gv.y + bv.y);
  hp[2] = (bf16_t)((v.z - mu) * rstd * gv.z + bv.z);
  hp[3] = (bf16_t)((v.w - mu) * rstd * gv.w + bv.w);
}

// ---- causal softmax over row t of S[z] (in-place, bf16, scale 1/32) ----
__global__ __launch_bounds__(256) void softmax_causal(bf16_t* __restrict__ S) {
  const int T = 2048;
  int t = blockIdx.x, z = blockIdx.y;
  bf16_t* row = S + (size_t)z * T * T + (size_t)t * T;
  int tid = threadIdx.x;
  float vals[8];
  float m = -1e30f;
#pragma unroll
  for (int i = 0; i < 8; ++i) {
    int s = tid + i * 256;
    float v = (s <= t) ? (float)row[s] * 0.03125f : -1e30f;
    vals[i] = v;
    m = fmaxf(m, v);
  }
  m = wred_max(m);
  __shared__ float shm[4], shs[4];
  int lane = tid & 63, wv = tid >> 6;
  if (lane == 0) shm[wv] = m;
  __syncthreads();
  m = fmaxf(fmaxf(shm[0], shm[1]), fmaxf(shm[2], shm[3]));
  float sum = 0.f;
#pragma unroll
  for (int i = 0; i < 8; ++i) {
    float e = (vals[i] > -1e29f) ? __expf(vals[i] - m) : 0.f;
    vals[i] = e;
    sum += e;
  }
  sum = wred_sum(sum);
  if (lane == 0) shs[wv] = sum;
  __syncthreads();
  sum = shs[0] + shs[1] + shs[2] + shs[3];
  float inv = 1.f / sum;
#pragma unroll
  for (int i = 0; i < 8; ++i) row[tid + i * 256] = (bf16_t)(vals[i] * inv);
}

// ---- per-row logsumexp + NLL ----
__global__ __launch_bounds__(256) void loss_rows(
    const float* __restrict__ logits, const int* __restrict__ tgt,
    float* __restrict__ nll) {
  const int V = 32000;
  int row = blockIdx.x;
  const float* p = logits + (size_t)row * V;
  int tid = threadIdx.x;
  float m = -1e30f, s = 0.f;
  for (int i = tid; i < V; i += 256) {
    float v = p[i];
    float nm = fmaxf(m, v);
    s = s * __expf(m - nm) + __expf(v - nm);
    m = nm;
  }
#pragma unroll
  for (int o = 32; o; o >>= 1) {
    float om = __shfl_xor(m, o, 64);
    float os = __shfl_xor(s, o, 64);
    float nm = fmaxf(m, om);
    s = s * __expf(m - nm) + os * __expf(om - nm);
    m = nm;
  }
  __shared__ float shm[4], shs[4];
  int lane = tid & 63, wv = tid >> 6;
  if (lane == 0) { shm[wv] = m; shs[wv] = s; }
  __syncthreads();
  if (tid == 0) {
    float M = shm[0], Ss = shs[0];
#pragma unroll
    for (int i2 = 1; i2 < 4; ++i2) {
      float nm = fmaxf(M, shm[i2]);
      Ss = Ss * __expf(M - nm) + shs[i2] * __expf(shm[i2] - nm);
      M = nm;
    }
    nll[row] = logf(Ss) + M - p[tgt[row]];
  }
}

__global__ __launch_bounds__(256) void loss_final_k(
    const float* __restrict__ nll, float* __restrict__ out) {
  int tid = threadIdx.x;
  float s = 0.f;
  for (int i = tid; i < 4096; i += 256) s += nll[i];
  s = wred_sum(s);
  __shared__ float sh[4];
  if ((tid & 63) == 0) sh[tid >> 6] = s;
  __syncthreads();
  if (tid == 0) out[0] = (sh[0] + sh[1] + sh[2] + sh[3]) * (1.f / 4096.f);
}

extern "C" void kernel_launch(void* const* d_in, const int* in_sizes, int n_in,
                              void* d_out, int out_size, void* d_ws,
                              size_t ws_size, hipStream_t stream) {
  (void)in_sizes; (void)n_in; (void)out_size; (void)ws_size;
  const int*   idx  = (const int*)d_in[0];
  const int*   tgt  = (const int*)d_in[1];
  const float* tok  = (const float*)d_in[2];
  const float* pos  = (const float*)d_in[3];
  const float* wq   = (const float*)d_in[4];
  const float* wk   = (const float*)d_in[5];
  const float* wv   = (const float*)d_in[6];
  const float* ln1g = (const float*)d_in[7];
  const float* ln1b = (const float*)d_in[8];
  const float* ln2g = (const float*)d_in[9];
  const float* ln2b = (const float*)d_in[10];
  const float* w1   = (const float*)d_in[11];
  const float* b1   = (const float*)d_in[12];
  const float* w2   = (const float*)d_in[13];
  const float* b2   = (const float*)d_in[14];
  const float* lmw  = (const float*)d_in[15];
  const float* lmb  = (const float*)d_in[16];

  float* logits = (float*)d_out;
  float* lossp = logits + (size_t)4096 * 32000;

  char* w = (char*)d_ws;
  size_t off = 0;
  auto alc = [&](size_t b) {
    char* p = w + off;
    off += (b + 255) & ~(size_t)255;
    return p;
  };
  float*  x    = (float*)alc((size_t)4096 * 1024 * 4);
  bf16_t* h    = (bf16_t*)alc((size_t)4096 * 1024 * 2);
  bf16_t* q    = (bf16_t*)alc((size_t)4096 * 1024 * 2);
  bf16_t* kk   = (bf16_t*)alc((size_t)4096 * 1024 * 2);
  bf16_t* vT   = (bf16_t*)alc((size_t)4096 * 1024 * 2);
  bf16_t* S    = (bf16_t*)alc((size_t)8 * 2048 * 2048 * 2);  // S/P, aliased by u
  float*  attn = (float*)alc((size_t)4096 * 1024 * 4);
  float*  x2   = (float*)alc((size_t)4096 * 1024 * 4);
  bf16_t* h2   = (bf16_t*)alc((size_t)4096 * 1024 * 2);
  bf16_t* xb   = (bf16_t*)alc((size_t)4096 * 1024 * 2);
  bf16_t* wqT  = (bf16_t*)alc((size_t)1024 * 1024 * 2);
  bf16_t* wkT  = (bf16_t*)alc((size_t)1024 * 1024 * 2);
  bf16_t* wvT  = (bf16_t*)alc((size_t)1024 * 1024 * 2);
  bf16_t* w1T  = (bf16_t*)alc((size_t)4096 * 1024 * 2);
  bf16_t* w2T  = (bf16_t*)alc((size_t)4096 * 1024 * 2);
  bf16_t* lmT  = (bf16_t*)alc((size_t)32000 * 1024 * 2);
  float*  nll  = (float*)alc((size_t)4096 * 4);
  bf16_t* u    = S;  // FFN hidden aliases S/P (disjoint phases)

  dim3 blk(256);

  // weight convert+transpose to bf16 [N,K]
  transpose_cast<<<dim3(8, 32, 4), blk, 0, stream>>>(wq, wqT, 1024, 256, 262144L, 262144L);
  transpose_cast<<<dim3(8, 32, 4), blk, 0, stream>>>(wk, wkT, 1024, 256, 262144L, 262144L);
  transpose_cast<<<dim3(8, 32, 4), blk, 0, stream>>>(wv, wvT, 1024, 256, 262144L, 262144L);
  transpose_cast<<<dim3(128, 32, 1), blk, 0, stream>>>(w1, w1T, 1024, 4096, 0L, 0L);
  transpose_cast<<<dim3(32, 128, 1), blk, 0, stream>>>(w2, w2T, 4096, 1024, 0L, 0L);
  transpose_cast<<<dim3(1000, 32, 1), blk, 0, stream>>>(lmw, lmT, 1024, 32000, 0L, 0L);

  embed_ln1<<<dim3(4096), blk, 0, stream>>>(idx, tok, pos, ln1g, ln1b, x, h);

  // q, k: [4096,1024] (layout [B,T,H,D]);  vT: per-head [D, B*T]
  gemm_bt<8><<<dim3(8, 32, 1), blk, 0, stream>>>(h, wqT, q, nullptr, nullptr,
      1024, 1024, 1024, 1024, 1, 0L, 0L, 0L, 0L, 0L, 0L);
  gemm_bt<8><<<dim3(8, 32, 1), blk, 0, stream>>>(h, wkT, kk, nullptr, nullptr,
      1024, 1024, 1024, 1024, 1, 0L, 0L, 0L, 0L, 0L, 0L);
  gemm_bt<8><<<dim3(32, 2, 4), blk, 0, stream>>>(wvT, h, vT, nullptr, nullptr,
      1024, 1024, 1024, 4096, 1, 262144L, 0L, 0L, 0L, 1048576L, 0L);

  // S = q @ k^T per (b,h), causal tiles skipped; bf16 out
  gemm_bt<24><<<dim3(16, 16, 8), blk, 0, stream>>>(q, kk, S, nullptr, nullptr,
      256, 1024, 1024, 2048, 4, 2097152L, 256L, 2097152L, 256L, 16777216L, 4194304L);
  softmax_causal<<<dim3(2048, 8), blk, 0, stream>>>(S);
  // attn = P @ V per (b,h), K limited to causal range; f32 out [B,H,T,D]
  gemm_bt<32><<<dim3(2, 16, 8), blk, 0, stream>>>(S, vT, attn, nullptr, nullptr,
      2048, 2048, 4096, 256, 4, 16777216L, 4194304L, 2048L, 1048576L, 2097152L, 524288L);

  ln2_res<<<dim3(4096), blk, 0, stream>>>(x, attn, ln2g, ln2b, x2, h2);

  // FFN
  gemm_bt<11><<<dim3(32, 32, 1), blk, 0, stream>>>(h2, w1T, u, b1, nullptr,
      1024, 1024, 1024, 4096, 1, 0L, 0L, 0L, 0L, 0L, 0L);
  gemm_bt<13><<<dim3(8, 32, 1), blk, 0, stream>>>(u, w2T, xb, b2, x2,
      4096, 4096, 4096, 1024, 1, 0L, 0L, 0L, 0L, 0L, 0L);

  // LM head -> fp32 logits in d_out
  gemm_bt<1><<<dim3(250, 32, 1), blk, 0, stream>>>(xb, lmT, logits, lmb, nullptr,
      1024, 1024, 1024, 32000, 1, 0L, 0L, 0L, 0L, 0L, 0L);

  loss_rows<<<dim3(4096), blk, 0, stream>>>(logits, tgt, nll);
  loss_final_k<<<dim3(1), blk, 0, stream>>>(nll, lossp);
}